// Round 9
// baseline (240.912 us; speedup 1.0000x reference)
//
#include <hip/hip_runtime.h>

// All inputs and the output are float32 (established rounds 0-3).
// R16: R15 hit 55us mega (occ 50%, VGPR 24, no spill) -- still latency/issue
// bound: ~268 scalar 4B weight loads/thread, only ~6-8 in flight (VGPR 24!).
// This round: 2 cols/thread, all weight loads float2 (8B/lane = coalescing
// sweet spot; half the load instructions, 2x FMA per LDS read), K-splits
// deepened: L3/L4 8x32K (32 f2 loads/thr), G2 head x K-quarter (64 f2), shared
// L1 192 f2 (was 384 scalar). Bodies keep acc<=8 + unroll 2 (<=~56 VGPR).
// Tripwires: mega WRITE_SIZE must stay 288KB, VGPR <= 64.

__device__ __forceinline__ float leaky(float v) { return v >= 0.f ? v : 0.2f * v; }

// ---------- D0: shared MLP + prebias. 88 blocks x 1024 thr.
// blocks 0..63 (b=blk): sh[b] = leaky(h[b] @ st_w1 + st_b1) @ st_w2 + st_b2
// blocks 64..87 (r=blk-64): re[r] = rm_b1[r] + rank_emb[r] @ rm_w1[r, 256:, :]
__global__ __launch_bounds__(1024, 4) void shared_kernel(
    const float* __restrict__ h,
    const float* __restrict__ st_w1, const float* __restrict__ st_b1,
    const float* __restrict__ st_w2, const float* __restrict__ st_b2,
    const float* __restrict__ rank_emb,
    const float* __restrict__ rm_w1, const float* __restrict__ rm_b1,
    float* __restrict__ sh, float* __restrict__ re)
{
    __shared__ __align__(16) float h_s[768];
    __shared__ __align__(16) float hid_s[512];
    __shared__ __align__(16) float ps[2048];   // viewed [4][512] or [8][256]
    const int tid = threadIdx.x;
    const int blk = blockIdx.x;
    if (blk < 64) {
        const int b = blk;
        if (tid < 192)
            ((float4*)h_s)[tid] = ((const float4*)(h + (size_t)b * 768))[tid];
        __syncthreads();
        // L1: 256 col-pairs x 4 K-groups (192 K each); float2 weights
        {
            const int cp = tid & 255, kg = tid >> 8;
            const int o = kg * 192, c0 = cp * 2;
            float a0 = 0.f, a1 = 0.f;
            const float* wp = st_w1 + (size_t)o * 512 + c0;
            #pragma unroll 2
            for (int k = 0; k < 192; k += 4) {
                float2 w0 = *(const float2*)&wp[(size_t)(k + 0) * 512];
                float2 w1 = *(const float2*)&wp[(size_t)(k + 1) * 512];
                float2 w2 = *(const float2*)&wp[(size_t)(k + 2) * 512];
                float2 w3 = *(const float2*)&wp[(size_t)(k + 3) * 512];
                float4 hv = *(const float4*)&h_s[o + k];
                a0 += hv.x * w0.x + hv.y * w1.x + hv.z * w2.x + hv.w * w3.x;
                a1 += hv.x * w0.y + hv.y * w1.y + hv.z * w2.y + hv.w * w3.y;
            }
            ps[kg * 512 + c0] = a0; ps[kg * 512 + c0 + 1] = a1;
        }
        __syncthreads();
        if (tid < 512)
            hid_s[tid] = leaky(st_b1[tid] + ps[tid] + ps[512 + tid]
                               + ps[1024 + tid] + ps[1536 + tid]);
        __syncthreads();
        // L2: 128 col-pairs x 8 K-groups (64 K each)
        {
            const int cp = tid & 127, kq = tid >> 7;
            const int o = kq * 64, c0 = cp * 2;
            float a0 = 0.f, a1 = 0.f;
            const float* wp = st_w2 + (size_t)o * 256 + c0;
            #pragma unroll 2
            for (int d = 0; d < 64; d += 4) {
                float2 w0 = *(const float2*)&wp[(size_t)(d + 0) * 256];
                float2 w1 = *(const float2*)&wp[(size_t)(d + 1) * 256];
                float2 w2 = *(const float2*)&wp[(size_t)(d + 2) * 256];
                float2 w3 = *(const float2*)&wp[(size_t)(d + 3) * 256];
                float4 s = *(const float4*)&hid_s[o + d];
                a0 += s.x * w0.x + s.y * w1.x + s.z * w2.x + s.w * w3.x;
                a1 += s.x * w0.y + s.y * w1.y + s.z * w2.y + s.w * w3.y;
            }
            ps[kq * 256 + c0] = a0; ps[kq * 256 + c0 + 1] = a1;
        }
        __syncthreads();
        if (tid < 256) {
            float v = st_b2[tid];
            #pragma unroll
            for (int q = 0; q < 8; ++q) v += ps[q * 256 + tid];
            sh[(size_t)b * 256 + tid] = v;
        }
    } else {
        const int r = blk - 64;
        if (tid < 64)
            ((float4*)h_s)[tid] = ((const float4*)(rank_emb + (size_t)r * 256))[tid];
        __syncthreads();
        // prebias: 128 col-pairs x 8 K-groups (32 K each)
        {
            const int cp = tid & 127, kq = tid >> 7;
            const int o = kq * 32, c0 = cp * 2;
            float a0 = 0.f, a1 = 0.f;
            const float* wb = rm_w1 + ((size_t)r * 512 + 256 + o) * 256 + c0;
            #pragma unroll 2
            for (int d = 0; d < 32; d += 4) {
                float2 w0 = *(const float2*)&wb[(size_t)(d + 0) * 256];
                float2 w1 = *(const float2*)&wb[(size_t)(d + 1) * 256];
                float2 w2 = *(const float2*)&wb[(size_t)(d + 2) * 256];
                float2 w3 = *(const float2*)&wb[(size_t)(d + 3) * 256];
                float4 e = *(const float4*)&h_s[o + d];
                a0 += e.x * w0.x + e.y * w1.x + e.z * w2.x + e.w * w3.x;
                a1 += e.x * w0.y + e.y * w1.y + e.z * w2.y + e.w * w3.y;
            }
            ps[kq * 256 + c0] = a0; ps[kq * 256 + c0 + 1] = a1;
        }
        __syncthreads();
        if (tid < 256) {
            float v = rm_b1[r * 256 + tid];
            #pragma unroll
            for (int q = 0; q < 8; ++q) v += ps[q * 256 + tid];
            re[(size_t)r * 256 + tid] = v;
        }
    }
}

// ---------- D1: mega-middle. 384 blocks x 1024 thr. blk -> (r = blk%24, bt = blk/24),
// 4 batch rows; cp = tid&127 (col-pair), kg = tid>>7 (0..7).
// L3/L4: kg = K-octant (32 K), acc[4][2], float2 weights, ps[8] partials.
// G2: kg = (kq<<1)|head, K-quarter 64, acc[4][2]. G3: 4-way K-split, 768 thr.
__global__ __launch_bounds__(1024, 8) void mega_kernel(
    const float* __restrict__ sh,
    const float* __restrict__ re,
    const float* __restrict__ rm_w1,
    const float* __restrict__ rm_w2, const float* __restrict__ rm_b2,
    const float* __restrict__ mx_w1, const float* __restrict__ mx_b1,
    const float* __restrict__ mx_w2, const float* __restrict__ mx_b2,
    const float* __restrict__ my_w1, const float* __restrict__ my_b1,
    const float* __restrict__ my_w2, const float* __restrict__ my_b2,
    const float* __restrict__ ax_w1, const float* __restrict__ ax_b1,
    const float* __restrict__ ax_w2, const float* __restrict__ ax_b2,
    const float* __restrict__ ay_w1, const float* __restrict__ ay_b1,
    const float* __restrict__ ay_w2, const float* __restrict__ ay_b2,
    float* __restrict__ Pcat)
{
    __shared__ __align__(16) float sh_s[4][256];     // 4 KB
    __shared__ __align__(16) float hdn_s[4][256];    // 4 KB
    __shared__ __align__(16) float rf_s[4][256];     // 4 KB
    __shared__ __align__(16) float hc_s[2][4][256];  // 8 KB
    __shared__ __align__(16) float ps[8][4][256];    // 32 KB (reused as psf)
    __shared__ __align__(16) float re_s[256];        // 1 KB   (total 53 KB)
    const int tid = threadIdx.x;
    const int blk = blockIdx.x;
    const int r = blk % 24;          // blk % 8 == r % 8: rank stays on one XCD
    const int bt = blk / 24;         // 0..15
    const int b0 = bt * 4;
    const int cp = tid & 127, kg = tid >> 7;
    const int c0 = cp * 2;

    // stage: 4 sh rows (256 float4) + re row (64 float4)
    if (tid < 256) {
        ((float4*)sh_s)[tid] = ((const float4*)sh)[(size_t)b0 * 64 + tid];
    } else if (tid < 320) {
        int j4 = tid - 256;
        ((float4*)re_s)[j4] = ((const float4*)re)[(size_t)r * 64 + j4];
    }
    __syncthreads();

    // L3 partial: K-octant kg (32 K) of sh @ rm_w1[r, :256, :], 4 rows x 2 cols
    {
        float a00 = 0.f, a01 = 0.f, a10 = 0.f, a11 = 0.f;
        float a20 = 0.f, a21 = 0.f, a30 = 0.f, a31 = 0.f;
        const int o = kg * 32;
        const float* wp = rm_w1 + ((size_t)r * 512 + o) * 256 + c0;
        #pragma unroll 2
        for (int d = 0; d < 32; d += 4) {
            float2 w0 = *(const float2*)&wp[(size_t)(d + 0) * 256];
            float2 w1 = *(const float2*)&wp[(size_t)(d + 1) * 256];
            float2 w2 = *(const float2*)&wp[(size_t)(d + 2) * 256];
            float2 w3 = *(const float2*)&wp[(size_t)(d + 3) * 256];
            float4 s0 = *(const float4*)&sh_s[0][o + d];
            float4 s1 = *(const float4*)&sh_s[1][o + d];
            float4 s2 = *(const float4*)&sh_s[2][o + d];
            float4 s3 = *(const float4*)&sh_s[3][o + d];
            a00 += s0.x * w0.x + s0.y * w1.x + s0.z * w2.x + s0.w * w3.x;
            a01 += s0.x * w0.y + s0.y * w1.y + s0.z * w2.y + s0.w * w3.y;
            a10 += s1.x * w0.x + s1.y * w1.x + s1.z * w2.x + s1.w * w3.x;
            a11 += s1.x * w0.y + s1.y * w1.y + s1.z * w2.y + s1.w * w3.y;
            a20 += s2.x * w0.x + s2.y * w1.x + s2.z * w2.x + s2.w * w3.x;
            a21 += s2.x * w0.y + s2.y * w1.y + s2.z * w2.y + s2.w * w3.y;
            a30 += s3.x * w0.x + s3.y * w1.x + s3.z * w2.x + s3.w * w3.x;
            a31 += s3.x * w0.y + s3.y * w1.y + s3.z * w2.y + s3.w * w3.y;
        }
        ps[kg][0][c0] = a00; ps[kg][0][c0 + 1] = a01;
        ps[kg][1][c0] = a10; ps[kg][1][c0 + 1] = a11;
        ps[kg][2][c0] = a20; ps[kg][2][c0 + 1] = a21;
        ps[kg][3][c0] = a30; ps[kg][3][c0 + 1] = a31;
    }
    __syncthreads();
    {
        int i = tid >> 8, c = tid & 255;
        float v = re_s[c];
        #pragma unroll
        for (int q = 0; q < 8; ++q) v += ps[q][i][c];
        hdn_s[i][c] = leaky(v);
    }
    __syncthreads();

    // L4 partial: K-octant kg of hdn @ rm_w2[r], 4 rows x 2 cols
    {
        float a00 = 0.f, a01 = 0.f, a10 = 0.f, a11 = 0.f;
        float a20 = 0.f, a21 = 0.f, a30 = 0.f, a31 = 0.f;
        const int o = kg * 32;
        const float* wp = rm_w2 + (size_t)r * 65536 + (size_t)o * 256 + c0;
        #pragma unroll 2
        for (int d = 0; d < 32; d += 4) {
            float2 w0 = *(const float2*)&wp[(size_t)(d + 0) * 256];
            float2 w1 = *(const float2*)&wp[(size_t)(d + 1) * 256];
            float2 w2 = *(const float2*)&wp[(size_t)(d + 2) * 256];
            float2 w3 = *(const float2*)&wp[(size_t)(d + 3) * 256];
            float4 s0 = *(const float4*)&hdn_s[0][o + d];
            float4 s1 = *(const float4*)&hdn_s[1][o + d];
            float4 s2 = *(const float4*)&hdn_s[2][o + d];
            float4 s3 = *(const float4*)&hdn_s[3][o + d];
            a00 += s0.x * w0.x + s0.y * w1.x + s0.z * w2.x + s0.w * w3.x;
            a01 += s0.x * w0.y + s0.y * w1.y + s0.z * w2.y + s0.w * w3.y;
            a10 += s1.x * w0.x + s1.y * w1.x + s1.z * w2.x + s1.w * w3.x;
            a11 += s1.x * w0.y + s1.y * w1.y + s1.z * w2.y + s1.w * w3.y;
            a20 += s2.x * w0.x + s2.y * w1.x + s2.z * w2.x + s2.w * w3.x;
            a21 += s2.x * w0.y + s2.y * w1.y + s2.z * w2.y + s2.w * w3.y;
            a30 += s3.x * w0.x + s3.y * w1.x + s3.z * w2.x + s3.w * w3.x;
            a31 += s3.x * w0.y + s3.y * w1.y + s3.z * w2.y + s3.w * w3.y;
        }
        ps[kg][0][c0] = a00; ps[kg][0][c0 + 1] = a01;
        ps[kg][1][c0] = a10; ps[kg][1][c0 + 1] = a11;
        ps[kg][2][c0] = a20; ps[kg][2][c0 + 1] = a21;
        ps[kg][3][c0] = a30; ps[kg][3][c0 + 1] = a31;
    }
    __syncthreads();
    {
        int i = tid >> 8, c = tid & 255;
        float v = rm_b2[r * 256 + c];
        #pragma unroll
        for (int q = 0; q < 8; ++q) v += ps[q][i][c];
        rf_s[i][c] = v;
    }
    __syncthreads();

    // head pointers: r<16: head0=mx(y=r), head1=my(y=16+r);
    // r>=16: rw=r-16: head0=ax(y=32+rw), head1=ay(y=40+rw)
    const float *W1_0, *B1_0, *W2_0, *B2_0, *W1_1, *B1_1, *W2_1, *B2_1;
    int y0, y1;
    if (r < 16) {
        y0 = r;       y1 = 16 + r;
        W1_0 = mx_w1 + (size_t)r * 65536;  B1_0 = mx_b1 + r * 256;
        W2_0 = mx_w2 + (size_t)r * 6144;   B2_0 = mx_b2 + r * 24;
        W1_1 = my_w1 + (size_t)r * 65536;  B1_1 = my_b1 + r * 256;
        W2_1 = my_w2 + (size_t)r * 6144;   B2_1 = my_b2 + r * 24;
    } else {
        int rw = r - 16;
        y0 = 32 + rw;  y1 = 40 + rw;
        W1_0 = ax_w1 + (size_t)rw * 65536; B1_0 = ax_b1 + rw * 256;
        W2_0 = ax_w2 + (size_t)rw * 6144;  B2_0 = ax_b2 + rw * 24;
        W1_1 = ay_w1 + (size_t)rw * 65536; B1_1 = ay_b1 + rw * 256;
        W2_1 = ay_w2 + (size_t)rw * 6144;  B2_1 = ay_b2 + rw * 24;
    }

    // G2 partial: kg = (kq<<1)|head -> head, K-quarter kq (64 K), 4 rows x 2 cols
    {
        const int hh = kg & 1, kq = kg >> 1;
        const int o = kq * 64;
        const float* wp = (hh ? W1_1 : W1_0) + (size_t)o * 256 + c0;
        float a00 = 0.f, a01 = 0.f, a10 = 0.f, a11 = 0.f;
        float a20 = 0.f, a21 = 0.f, a30 = 0.f, a31 = 0.f;
        #pragma unroll 2
        for (int d = 0; d < 64; d += 4) {
            float2 w0 = *(const float2*)&wp[(size_t)(d + 0) * 256];
            float2 w1 = *(const float2*)&wp[(size_t)(d + 1) * 256];
            float2 w2 = *(const float2*)&wp[(size_t)(d + 2) * 256];
            float2 w3 = *(const float2*)&wp[(size_t)(d + 3) * 256];
            float4 s0 = *(const float4*)&rf_s[0][o + d];
            float4 s1 = *(const float4*)&rf_s[1][o + d];
            float4 s2 = *(const float4*)&rf_s[2][o + d];
            float4 s3 = *(const float4*)&rf_s[3][o + d];
            a00 += s0.x * w0.x + s0.y * w1.x + s0.z * w2.x + s0.w * w3.x;
            a01 += s0.x * w0.y + s0.y * w1.y + s0.z * w2.y + s0.w * w3.y;
            a10 += s1.x * w0.x + s1.y * w1.x + s1.z * w2.x + s1.w * w3.x;
            a11 += s1.x * w0.y + s1.y * w1.y + s1.z * w2.y + s1.w * w3.y;
            a20 += s2.x * w0.x + s2.y * w1.x + s2.z * w2.x + s2.w * w3.x;
            a21 += s2.x * w0.y + s2.y * w1.y + s2.z * w2.y + s2.w * w3.y;
            a30 += s3.x * w0.x + s3.y * w1.x + s3.z * w2.x + s3.w * w3.x;
            a31 += s3.x * w0.y + s3.y * w1.y + s3.z * w2.y + s3.w * w3.y;
        }
        ps[kg][0][c0] = a00; ps[kg][0][c0 + 1] = a01;
        ps[kg][1][c0] = a10; ps[kg][1][c0 + 1] = a11;
        ps[kg][2][c0] = a20; ps[kg][2][c0 + 1] = a21;
        ps[kg][3][c0] = a30; ps[kg][3][c0 + 1] = a31;
    }
    __syncthreads();
    // combine hc: head h partials at kg = {h, 2+h, 4+h, 6+h}
    #pragma unroll
    for (int t = 0; t < 2; ++t) {
        int idx = tid + t * 1024;
        int h2 = idx >> 10, rem = idx & 1023;
        int i = rem >> 8, c = rem & 255;
        hc_s[h2][i][c] = leaky((h2 ? B1_1 : B1_0)[c]
                               + ps[h2][i][c] + ps[2 + h2][i][c]
                               + ps[4 + h2][i][c] + ps[6 + h2][i][c]);
    }
    __syncthreads();

    // G3 partial: 2 heads x 4 rows x 24 cols x 4 K-quarters(64) = 768 threads
    float* psf = &ps[0][0][0];
    if (tid < 768) {
        int o = tid >> 2, kq = tid & 3;
        int h2 = o / 96, rc = o % 96;
        int row = rc / 24, cj = rc - row * 24;
        const float* wp = (h2 ? W2_1 : W2_0) + (size_t)(kq * 64) * 24 + cj;
        const float* hp = &hc_s[h2][row][kq * 64];
        float acc = 0.f;
        #pragma unroll 4
        for (int d = 0; d < 64; d += 4) {
            float w0 = wp[(d + 0) * 24], w1 = wp[(d + 1) * 24];
            float w2 = wp[(d + 2) * 24], w3 = wp[(d + 3) * 24];
            float4 s = *(const float4*)&hp[d];
            acc += s.x * w0 + s.y * w1 + s.z * w2 + s.w * w3;
        }
        psf[tid] = acc;
    }
    __syncthreads();
    if (tid < 192) {
        int h2 = tid / 96, rc = tid - h2 * 96;
        int row = rc / 24, cj = rc - row * 24;
        float v = (h2 ? B2_1 : B2_0)[cj]
                + psf[tid * 4] + psf[tid * 4 + 1] + psf[tid * 4 + 2] + psf[tid * 4 + 3];
        int y = h2 ? y1 : y0;
        Pcat[(size_t)(b0 + row) * 1152 + y * 24 + cj] = v;
    }
}

// ---------- D2: fused spline + depth (unchanged).
// Pcat rows: [Px_m 0..15, Py_m 16..31, Px_a 32..39, Py_a 40..47]
__global__ __launch_bounds__(256, 2) void depth_fused_kernel(
    const float* __restrict__ Pcat,
    const float* __restrict__ mult_w, const float* __restrict__ addx_w,
    const float* __restrict__ addy_w, const float* __restrict__ gbias,
    float* __restrict__ out)
{
    __shared__ float cp[48][25];
    __shared__ float sw[33];
    __shared__ __align__(16) float u_s[16][132];
    __shared__ __align__(16) float v_s[16][132];
    __shared__ float dx_s[128], dy_s[128];
    const int tid = threadIdx.x;
    const int b = blockIdx.z, h0 = blockIdx.y * 128, w0 = blockIdx.x * 128;
    for (int idx = tid; idx < 1152; idx += 256)
        cp[idx / 24][idx % 24] = Pcat[(size_t)b * 1152 + idx];
    if (tid == 0) {
        float e[16], m, s;
        m = -1e30f; for (int i = 0; i < 16; ++i) m = fmaxf(m, mult_w[i]);
        s = 0.f;    for (int i = 0; i < 16; ++i) { e[i] = __expf(mult_w[i] - m); s += e[i]; }
        for (int i = 0; i < 16; ++i) sw[i] = e[i] / s;
        m = -1e30f; for (int i = 0; i < 8; ++i) m = fmaxf(m, addx_w[i]);
        s = 0.f;    for (int i = 0; i < 8; ++i) { e[i] = __expf(addx_w[i] - m); s += e[i]; }
        for (int i = 0; i < 8; ++i) sw[16 + i] = e[i] / s;
        m = -1e30f; for (int i = 0; i < 8; ++i) m = fmaxf(m, addy_w[i]);
        s = 0.f;    for (int i = 0; i < 8; ++i) { e[i] = __expf(addy_w[i] - m); s += e[i]; }
        for (int i = 0; i < 8; ++i) sw[24 + i] = e[i] / s;
        sw[32] = gbias[0];
    }
    __syncthreads();
    {
        const int local = tid & 127;
        const int gpos = (tid < 128 ? w0 : h0) + local;
        const float eps = 0.001f;
        float t = eps + (float)gpos * ((1.f - 2.f * eps) / 511.f);
        float ts = t * 23.f;
        int seg = (int)ts; if (seg > 22) seg = 22;
        float tau = ts - (float)seg;
        tau = fminf(fmaxf(tau, 0.f), 0.9999f);
        float t2 = tau * tau, t3 = t2 * tau;
        float h00 = 2.f * t3 - 3.f * t2 + 1.f;
        float h10 = t3 - 2.f * t2 + tau;
        float h01 = -2.f * t3 + 3.f * t2;
        float h11 = t3 - t2;
        int sm1 = seg > 0 ? seg - 1 : 0;
        int s1 = seg + 1;
        int sp2 = s1 < 23 ? s1 + 1 : 23;
        const float msc = 0.5f / 23.f;
        auto spl = [&](int row) -> float {
            float pk = cp[row][seg], pk1 = cp[row][s1];
            float mk  = msc * (pk1 - cp[row][sm1]);
            float mk1 = msc * (cp[row][sp2] - pk);
            return h00 * pk + h10 * mk + h01 * pk1 + h11 * mk1;
        };
        if (tid < 128) {
            #pragma unroll
            for (int r = 0; r < 16; ++r) u_s[r][local] = sw[r] * spl(r);
            float dx = sw[32];
            #pragma unroll
            for (int r = 0; r < 8; ++r) dx += sw[16 + r] * spl(32 + r);
            dx_s[local] = dx;
        } else {
            #pragma unroll
            for (int r = 0; r < 16; ++r) v_s[r][local] = spl(16 + r);
            float dy = 0.f;
            #pragma unroll
            for (int r = 0; r < 8; ++r) dy += sw[24 + r] * spl(40 + r);
            dy_s[local] = dy;
        }
    }
    __syncthreads();
    const int tw = tid & 15, th = tid >> 4;
    float acc[8][8];
    #pragma unroll
    for (int i = 0; i < 8; ++i)
        #pragma unroll
        for (int j = 0; j < 8; ++j) acc[i][j] = 0.f;
    #pragma unroll
    for (int r = 0; r < 16; ++r) {
        float4 va0 = *(const float4*)&v_s[r][th * 8];
        float4 va1 = *(const float4*)&v_s[r][th * 8 + 4];
        float4 ub0 = *(const float4*)&u_s[r][tw * 8];
        float4 ub1 = *(const float4*)&u_s[r][tw * 8 + 4];
        float va[8] = {va0.x, va0.y, va0.z, va0.w, va1.x, va1.y, va1.z, va1.w};
        float ub[8] = {ub0.x, ub0.y, ub0.z, ub0.w, ub1.x, ub1.y, ub1.z, ub1.w};
        #pragma unroll
        for (int i = 0; i < 8; ++i)
            #pragma unroll
            for (int j = 0; j < 8; ++j)
                acc[i][j] += va[i] * ub[j];
    }
    #pragma unroll
    for (int i = 0; i < 8; ++i) {
        float dyh = dy_s[th * 8 + i];
        float* op = out + (size_t)b * 262144 + (size_t)(h0 + th * 8 + i) * 512 + w0 + tw * 8;
        float4 o0, o1;
        o0.x = acc[i][0] + dx_s[tw * 8 + 0] + dyh;
        o0.y = acc[i][1] + dx_s[tw * 8 + 1] + dyh;
        o0.z = acc[i][2] + dx_s[tw * 8 + 2] + dyh;
        o0.w = acc[i][3] + dx_s[tw * 8 + 3] + dyh;
        o1.x = acc[i][4] + dx_s[tw * 8 + 4] + dyh;
        o1.y = acc[i][5] + dx_s[tw * 8 + 5] + dyh;
        o1.z = acc[i][6] + dx_s[tw * 8 + 6] + dyh;
        o1.w = acc[i][7] + dx_s[tw * 8 + 7] + dyh;
        *(float4*)op = o0;
        *(float4*)(op + 4) = o1;
    }
}

// ---------- host ----------
extern "C" void kernel_launch(void* const* d_in, const int* in_sizes, int n_in,
                              void* d_out, int out_size, void* d_ws, size_t ws_size,
                              hipStream_t stream) {
    const float* in_h     = (const float*)d_in[0];
    const float* rank_emb = (const float*)d_in[1];
    const float* st_w1    = (const float*)d_in[2];
    const float* st_b1    = (const float*)d_in[3];
    const float* st_w2    = (const float*)d_in[4];
    const float* st_b2    = (const float*)d_in[5];
    const float* rm_w1    = (const float*)d_in[6];
    const float* rm_b1    = (const float*)d_in[7];
    const float* rm_w2    = (const float*)d_in[8];
    const float* rm_b2    = (const float*)d_in[9];
    const float* mx_w1    = (const float*)d_in[10];
    const float* mx_b1    = (const float*)d_in[11];
    const float* mx_w2    = (const float*)d_in[12];
    const float* mx_b2    = (const float*)d_in[13];
    const float* my_w1    = (const float*)d_in[14];
    const float* my_b1    = (const float*)d_in[15];
    const float* my_w2    = (const float*)d_in[16];
    const float* my_b2    = (const float*)d_in[17];
    const float* ax_w1    = (const float*)d_in[18];
    const float* ax_b1    = (const float*)d_in[19];
    const float* ax_w2    = (const float*)d_in[20];
    const float* ax_b2    = (const float*)d_in[21];
    const float* ay_w1    = (const float*)d_in[22];
    const float* ay_b1    = (const float*)d_in[23];
    const float* ay_w2    = (const float*)d_in[24];
    const float* ay_b2    = (const float*)d_in[25];
    const float* mult_w   = (const float*)d_in[26];
    const float* addx_w   = (const float*)d_in[27];
    const float* addy_w   = (const float*)d_in[28];
    const float* gbias    = (const float*)d_in[29];
    (void)in_sizes; (void)n_in; (void)out_size; (void)ws_size;

    float* ws = (float*)d_ws;
    float* Pcat  = ws;               // 64x48x24 = 73728 floats
    float* shbuf = ws + 73728;       // 64x256   = 16384 floats
    float* rebuf = ws + 90112;       // 24x256   = 6144 floats

    // D0: shared MLP (L1+L2 fused, per-batch-row) + prebias
    shared_kernel<<<88, 1024, 0, stream>>>(in_h, st_w1, st_b1, st_w2, st_b2,
                                           rank_emb, rm_w1, rm_b1, shbuf, rebuf);

    // D1: mega-middle -> Pcat (384 blocks x 1024 thr, XCD-clustered by rank)
    mega_kernel<<<384, 1024, 0, stream>>>(
        shbuf, rebuf,
        rm_w1, rm_w2, rm_b2,
        mx_w1, mx_b1, mx_w2, mx_b2,
        my_w1, my_b1, my_w2, my_b2,
        ax_w1, ax_b1, ax_w2, ax_b2,
        ay_w1, ay_b1, ay_w2, ay_b2,
        Pcat);

    // D2: fused spline + depth
    depth_fused_kernel<<<dim3(4, 4, 64), 256, 0, stream>>>(
        Pcat, mult_w, addx_w, addy_w, gbias, (float*)d_out);
}